// Round 16
// baseline (379.752 us; speedup 1.0000x reference)
//
#include <hip/hip_runtime.h>
#include <hip/hip_bf16.h>
#include <stdint.h>

// ---------- helpers ----------
typedef __attribute__((ext_vector_type(8))) int v8i;
typedef __attribute__((ext_vector_type(4))) float f32x4;

__device__ __forceinline__ unsigned short f2bf(float f) {
  union { float f; unsigned int u; } v; v.f = f;
  unsigned int r = (v.u + 0x7fffu + ((v.u >> 16) & 1u)) >> 16;
  return (unsigned short)r;
}
__device__ __forceinline__ float bf2f(unsigned short h) {
  union { float f; unsigned int u; } v; v.u = ((unsigned int)h) << 16; return v.f;
}
// fp8 e4m3 (OCP) converts via HW packer
__device__ __forceinline__ unsigned char f2fp8(float f) {
  int r = __builtin_amdgcn_cvt_pk_fp8_f32(f, 0.f, 0, false);
  return (unsigned char)(r & 0xff);
}
__device__ __forceinline__ unsigned int f2fp8x4(float a, float b, float c, float d) {
  int r = __builtin_amdgcn_cvt_pk_fp8_f32(a, b, 0, false);
  r = __builtin_amdgcn_cvt_pk_fp8_f32(c, d, r, true);
  return (unsigned int)r;
}
// build v8i MFMA operand from two int4 register quads (static indices -> regs)
__device__ __forceinline__ v8i mkv8(int4 lo, int4 hi) {
  v8i r;
  r[0] = lo.x; r[1] = lo.y; r[2] = lo.z; r[3] = lo.w;
  r[4] = hi.x; r[5] = hi.y; r[6] = hi.z; r[7] = hi.w;
  return r;
}

// async global->LDS, 16B per lane; lds base wave-uniform, HW adds lane*16
__device__ __forceinline__ void async_copy16(const unsigned char* g, unsigned char* lds_base) {
  __builtin_amdgcn_global_load_lds(
      (const __attribute__((address_space(1))) unsigned int*)g,
      (__attribute__((address_space(3))) unsigned int*)lds_base,
      16, 0, 0);
}

// ---------- fp32 -> fp8 convert (two arrays, scale 16) ----------
__global__ __launch_bounds__(256) void cvt2_kernel(const float* __restrict__ s1,
                                                   unsigned int* __restrict__ d1, int n1_4,
                                                   const float* __restrict__ s2,
                                                   unsigned int* __restrict__ d2, int n2_4) {
  int i = blockIdx.x * 256 + threadIdx.x;
  const float* s; unsigned int* d; int idx;
  if (i < n1_4) { s = s1; d = d1; idx = i; }
  else if (i < n1_4 + n2_4) { s = s2; d = d2; idx = i - n1_4; }
  else return;
  float4 v = ((const float4*)s)[idx];
  d[idx] = f2fp8x4(v.x * 16.f, v.y * 16.f, v.z * 16.f, v.w * 16.f);
}

// ---------- LayerNorm: one block per row of 1024, fp8 out (scale 1) ----------
__global__ __launch_bounds__(256) void ln_kernel(const float* __restrict__ x,
                                                 const float* __restrict__ gamma,
                                                 const float* __restrict__ beta,
                                                 unsigned int* __restrict__ h) {
  const int row = blockIdx.x;
  const int t = threadIdx.x;
  const float4 v = ((const float4*)(x + (size_t)row * 1024))[t];
  float s  = v.x + v.y + v.z + v.w;
  float s2 = v.x*v.x + v.y*v.y + v.z*v.z + v.w*v.w;
#pragma unroll
  for (int o = 32; o > 0; o >>= 1) {
    s  += __shfl_down(s,  o, 64);
    s2 += __shfl_down(s2, o, 64);
  }
  __shared__ float rs[4], rs2[4];
  const int wid = t >> 6;
  if ((t & 63) == 0) { rs[wid] = s; rs2[wid] = s2; }
  __syncthreads();
  const float S  = rs[0] + rs[1] + rs[2] + rs[3];
  const float S2 = rs2[0] + rs2[1] + rs2[2] + rs2[3];
  const float mu  = S * (1.f / 1024.f);
  const float inv = rsqrtf(S2 * (1.f / 1024.f) - mu * mu + 1e-5f);
  const float4 g = ((const float4*)gamma)[t];
  const float4 b = ((const float4*)beta)[t];
  h[row * 256 + t] = f2fp8x4((v.x - mu) * inv * g.x + b.x,
                             (v.y - mu) * inv * g.y + b.y,
                             (v.z - mu) * inv * g.z + b.z,
                             (v.w - mu) * inv * g.w + b.w);
}

// ---------- fp8 MX GEMM: 128x128 tile, BK=128 bytes, NBUF=2, 2 blocks/CU ----------
// R16 = R12 base (proven best: 43.3us GEMM3, no swizzle — R15 proved T1
// chunking NEGATIVE here: it breaks natural cross-XCD panel sharing,
// FETCH 49->78MB) + fused GEMM1 epilogue producing ALL downstream tensors:
//   band bn<2048  : u_bf16[row][col]            (U for GEMM3 epilogue)
//   band <4096    : vT_f8[(col-2048)][row] transposed, 4 rows packed in one
//                   u32 (acc rows r=0..3 are consecutive & 4-aligned)
//   band ==4096   : q_f8/k_f8 = 16*(base*qk_w[s]+qk_b[s]) from fp32 base
// This deletes transpose_v + qk_kernel + the 34MB uv_bf buffer.
// Branch is per-BLOCK uniform (128-col band never straddles regions).
// Schedule per K-tile: { STAGE(t+1 -> wb) ; READ+MFMA(rb) ; vmcnt(0) ;
// barrier } — 2 blocks/CU co-residency hides stage/drain (m114); races as
// derived in R12 (reads(t) after prior iter's vmcnt(0)+barrier; stage(t+1)
// overwrites buf read at t-1, separated by that iter's barrier).
// LDS: 16B-slot XOR swizzle (source slot16^(row&7), read (2kg)^r7/(2kg+1)^r7;
// rule #21 both-sides; numerically proven R6+).
// MFMA: v_mfma_scale_f32_16x16x128_f8f6f4, fp8/fp8, unit scales.
// 8 waves = 2Mx4N, wave tile 64x32, acc[4][2]. VGPR ~52 + 32 AGPR (no spill).
// EPI 0: fused uv epilogue (above)
// EPI 1: 8*max(acc,0)^2               -> fp8 D    (= 2^26 * kernel_true)
// EPI 2: u * acc * 2^-2               -> fp8 D    (= 2^24 * ug_true)
// EPI 3: acc*2^-28 + bias[col] + X    -> f32 D
template <int EPI, int KTOT>
__global__ __launch_bounds__(512, 4)
void gemm_f8(const unsigned char* __restrict__ A, int lda,
             const unsigned char* __restrict__ B, int ldb,
             void* __restrict__ D, int ldd,
             const float* __restrict__ bias,
             const unsigned short* __restrict__ U, int ldu,
             const float* __restrict__ X, int ldx,
             unsigned char* __restrict__ vT, int ldvt,
             unsigned char* __restrict__ qo,
             unsigned char* __restrict__ ko,
             const float* __restrict__ W2) {
  constexpr int NT   = KTOT / 128;
  constexpr int NBUF = (NT == 1) ? 1 : 2;
  constexpr int NN   = 2;
  constexpr int WN   = 32;

  __shared__ __align__(64) unsigned char As[NBUF][128 * 128];   // 16KB per buf
  __shared__ __align__(64) unsigned char Bs[NBUF][128 * 128];   // 16KB per buf

  const int tid  = threadIdx.x;
  const int wid  = tid >> 6;
  const int lane = tid & 63;
  const int bm = blockIdx.x * 128;
  const int bn = blockIdx.y * 128;
  const int wr = wid >> 2;          // 0..1 -> rows wr*64
  const int wc = wid & 3;           // 0..3 -> cols wc*32
  const int frow = lane & 15;
  const int r7   = frow & 7;
  const int kg   = lane >> 4;
  const int s0   = ((2 * kg)     ^ r7) * 16;   // byte slot of K-window lo 16B
  const int s1   = ((2 * kg + 1) ^ r7) * 16;   // byte slot of K-window hi 16B

  // staging: per gload instr, 512 threads cover 64 rows x 128B (wave = 8 rows);
  // LDS[row][slot16] = G[row][slot16 ^ (row&7)] via pre-swizzled source
  const int srow  = tid >> 3;
  const int sslot = (tid & 7) ^ (srow & 7);
  const unsigned char* pA = A + (size_t)(bm + srow) * lda + sslot * 16;
  const unsigned char* pB = B + (size_t)(bn + srow) * ldb + sslot * 16;

#define STAGE(bufidx, k0)                                                                     \
  {                                                                                           \
    _Pragma("unroll")                                                                         \
    for (int i = 0; i < 2; ++i)                                                               \
      async_copy16(pA + (size_t)(i * 64) * lda + (k0), &As[bufidx][(i * 64 + wid * 8) * 128]);\
    _Pragma("unroll")                                                                         \
    for (int j = 0; j < 2; ++j)                                                               \
      async_copy16(pB + (size_t)(j * 64) * ldb + (k0), &Bs[bufidx][(j * 64 + wid * 8) * 128]);\
  }

#define READ_FRAGS(rbuf)                                                                      \
  {                                                                                           \
    _Pragma("unroll")                                                                         \
    for (int m = 0; m < 4; ++m) {                                                             \
      const int base = (wr * 64 + m * 16 + frow) * 128;                                       \
      la[m] = *(const int4*)&As[rbuf][base + s0];                                             \
      ha[m] = *(const int4*)&As[rbuf][base + s1];                                             \
    }                                                                                         \
    _Pragma("unroll")                                                                         \
    for (int n = 0; n < NN; ++n) {                                                            \
      const int base = (wc * WN + n * 16 + frow) * 128;                                       \
      lb[n] = *(const int4*)&Bs[rbuf][base + s0];                                             \
      hb[n] = *(const int4*)&Bs[rbuf][base + s1];                                             \
    }                                                                                         \
  }

#define MFMA_ALL()                                                                            \
  {                                                                                           \
    _Pragma("unroll")                                                                         \
    for (int m = 0; m < 4; ++m) {                                                             \
      const v8i am = mkv8(la[m], ha[m]);                                                      \
      _Pragma("unroll")                                                                       \
      for (int n = 0; n < NN; ++n)                                                            \
        acc[m][n] = __builtin_amdgcn_mfma_scale_f32_16x16x128_f8f6f4(                         \
            am, mkv8(lb[n], hb[n]), acc[m][n], 0, 0, 0, 0x7f7f7f7f, 0, 0x7f7f7f7f);           \
    }                                                                                         \
  }

  f32x4 acc[4][NN] = {};
  int4 la[4], ha[4], lb[NN], hb[NN];

  if constexpr (NT == 1) {
    STAGE(0, 0);
    asm volatile("s_waitcnt vmcnt(0)" ::: "memory");
    __builtin_amdgcn_s_barrier();
    READ_FRAGS(0);
    MFMA_ALL();
  } else {
    STAGE(0, 0);
    asm volatile("s_waitcnt vmcnt(0)" ::: "memory");
    __builtin_amdgcn_s_barrier();
    __builtin_amdgcn_sched_barrier(0);
    for (int t = 0; t < NT; ++t) {
      if (t + 1 < NT) STAGE((t + 1) & 1, ((size_t)(t + 1)) << 7);
      READ_FRAGS(t & 1);
      __builtin_amdgcn_s_setprio(1);
      MFMA_ALL();
      __builtin_amdgcn_s_setprio(0);
      __builtin_amdgcn_sched_barrier(0);
      asm volatile("s_waitcnt vmcnt(0)" ::: "memory");
      __builtin_amdgcn_s_barrier();
      __builtin_amdgcn_sched_barrier(0);
    }
  }

#undef STAGE
#undef READ_FRAGS
#undef MFMA_ALL

  // epilogue (C/D layout: col=lane&15, row=(lane>>4)*4+r — shape-determined)
  const int rbase = (lane >> 4) * 4;
  const int cloc  = lane & 15;
#pragma unroll
  for (int m = 0; m < 4; ++m) {
#pragma unroll
    for (int n = 0; n < NN; ++n) {
      const int col  = bn + wc * WN + n * 16 + cloc;
      const int row0 = bm + wr * 64 + m * 16 + rbase;
      if constexpr (EPI == 0) {
        // fused uv epilogue: silu(acc/16 + uv_b[col]) -> {u | vT | q,k}
        float vv[4];
#pragma unroll
        for (int r = 0; r < 4; ++r) {
          float v = acc[m][n][r] * (1.f / 16.f) + bias[col];
          vv[r] = v / (1.f + __expf(-v));
        }
        if (bn < 2048) {            // u band: bf16 row-major
#pragma unroll
          for (int r = 0; r < 4; ++r)
            ((unsigned short*)D)[(size_t)(row0 + r) * ldd + col] = f2bf(vv[r]);
        } else if (bn < 4096) {     // v band: fp8, transposed, 4 rows packed
          *(unsigned int*)(vT + (size_t)(col - 2048) * ldvt + row0) =
              f2fp8x4(vv[0], vv[1], vv[2], vv[3]);
        } else {                    // qk band: s = col - 4096
          const int s = col - 4096;
          const float qw = X[s], qb = W2[s], kw = X[128 + s], kb = W2[128 + s];
#pragma unroll
          for (int r = 0; r < 4; ++r) {
            qo[(size_t)(row0 + r) * 128 + s] = f2fp8(16.f * (vv[r] * qw + qb));
            ko[(size_t)(row0 + r) * 128 + s] = f2fp8(16.f * (vv[r] * kw + kb));
          }
        }
      } else {
#pragma unroll
        for (int r = 0; r < 4; ++r) {
          const int row = row0 + r;
          float v = acc[m][n][r];
          if constexpr (EPI == 1) {
            float z = fmaxf(v, 0.f);
            ((unsigned char*)D)[(size_t)row * ldd + col] = f2fp8(8.f * z * z);
          } else if constexpr (EPI == 2) {
            float u = bf2f(U[(size_t)row * ldu + col]);
            ((unsigned char*)D)[(size_t)row * ldd + col] = f2fp8(u * v * 0.25f);
          } else {
            ((float*)D)[(size_t)row * ldd + col] =
                v * (1.f / 268435456.f) + bias[col] + X[(size_t)row * ldx + col];
          }
        }
      }
    }
  }
}

// ---------- launch ----------
extern "C" void kernel_launch(void* const* d_in, const int* in_sizes, int n_in,
                              void* d_out, int out_size, void* d_ws, size_t ws_size,
                              hipStream_t stream) {
  const float* x    = (const float*)d_in[0];
  const float* ln_g = (const float*)d_in[1];
  const float* ln_b = (const float*)d_in[2];
  const float* uv_w = (const float*)d_in[3];
  const float* uv_b = (const float*)d_in[4];
  const float* qk_w = (const float*)d_in[5];
  const float* qk_b = (const float*)d_in[6];
  const float* o_w  = (const float*)d_in[7];
  const float* o_b  = (const float*)d_in[8];
  float* out = (float*)d_out;

  const int H = 1024, E = 2048, S = 128;
  const int NU = 2 * E + S;          // 4224
  const int n = in_sizes[0] / H;     // 4096

  char* p = (char*)d_ws;
  unsigned char* h_f8   = (unsigned char*)p; p += (size_t)n * H;
  unsigned char* uvw_f8 = (unsigned char*)p; p += (size_t)NU * H;
  unsigned char* ow_f8  = (unsigned char*)p; p += (size_t)H * E;
  unsigned short* u_bf  = (unsigned short*)p; p += (size_t)n * E * 2;
  unsigned char* q_f8   = (unsigned char*)p; p += (size_t)n * S;
  unsigned char* k_f8   = (unsigned char*)p; p += (size_t)n * S;
  unsigned char* vT_f8  = (unsigned char*)p; p += (size_t)E * n;
  unsigned char* ker_f8 = (unsigned char*)p; p += (size_t)n * n;
  unsigned char* ug_f8  = (unsigned char*)p; p += (size_t)n * E;

  const int n1_4 = NU * H / 4, n2_4 = H * E / 4;
  cvt2_kernel<<<(n1_4 + n2_4 + 255) / 256, 256, 0, stream>>>(
      uv_w, (unsigned int*)uvw_f8, n1_4, o_w, (unsigned int*)ow_f8, n2_4);

  ln_kernel<<<n, 256, 0, stream>>>(x, ln_g, ln_b, (unsigned int*)h_f8);

  // Fused uv GEMM: silu(h @ uv_w^T + uv_b) -> u_bf / vT_f8(transposed) / q,k
  // M=4096 N=4224 K=1024 (NT=8) ; 1056 blocks
  gemm_f8<0, 1024><<<dim3(n / 128, NU / 128), 512, 0, stream>>>(
      h_f8, H, uvw_f8, H, u_bf, E, uv_b, nullptr, 0, qk_w, 0,
      vT_f8, n, q_f8, k_f8, qk_b);

  // ker_f8 = 2^26 * relu(qk/sqrt(128))^2   M=N=4096 K=128 (NT=1) ; 1024 blocks, 4/CU
  gemm_f8<1, 128><<<dim3(n / 128, n / 128), 512, 0, stream>>>(
      q_f8, S, k_f8, S, ker_f8, n, nullptr, nullptr, 0, nullptr, 0,
      nullptr, 0, nullptr, nullptr, nullptr);

  // ug_f8 = 2^24 * u * (kernel @ v)   M=4096 N=2048 K=4096 (NT=32) ; 512 blocks, 2/CU
  gemm_f8<2, 4096><<<dim3(n / 128, E / 128), 512, 0, stream>>>(
      ker_f8, n, vT_f8, n, ug_f8, E, nullptr, u_bf, E, nullptr, 0,
      nullptr, 0, nullptr, nullptr, nullptr);

  // out = ug @ o_w^T + o_b + x   M=4096 N=1024 K=2048 (NT=16) ; 256 blocks
  gemm_f8<3, 2048><<<dim3(n / 128, H / 128), 512, 0, stream>>>(
      ug_f8, E, ow_f8, E, out, H, o_b, nullptr, 0, x, H,
      nullptr, 0, nullptr, nullptr, nullptr);
}

// Round 17
// 125.636 us; speedup vs baseline: 3.0226x; 3.0226x over previous
//
#include <hip/hip_runtime.h>
#include <hip/hip_bf16.h>
#include <stdint.h>

// ---------- helpers ----------
typedef __attribute__((ext_vector_type(8))) int v8i;
typedef __attribute__((ext_vector_type(4))) float f32x4;

__device__ __forceinline__ unsigned short f2bf(float f) {
  union { float f; unsigned int u; } v; v.f = f;
  unsigned int r = (v.u + 0x7fffu + ((v.u >> 16) & 1u)) >> 16;
  return (unsigned short)r;
}
__device__ __forceinline__ float bf2f(unsigned short h) {
  union { float f; unsigned int u; } v; v.u = ((unsigned int)h) << 16; return v.f;
}
// fp8 e4m3 (OCP) converts via HW packer
__device__ __forceinline__ unsigned char f2fp8(float f) {
  int r = __builtin_amdgcn_cvt_pk_fp8_f32(f, 0.f, 0, false);
  return (unsigned char)(r & 0xff);
}
__device__ __forceinline__ unsigned int f2fp8x4(float a, float b, float c, float d) {
  int r = __builtin_amdgcn_cvt_pk_fp8_f32(a, b, 0, false);
  r = __builtin_amdgcn_cvt_pk_fp8_f32(c, d, r, true);
  return (unsigned int)r;
}
// build v8i MFMA operand from two int4 register quads (static indices -> regs)
__device__ __forceinline__ v8i mkv8(int4 lo, int4 hi) {
  v8i r;
  r[0] = lo.x; r[1] = lo.y; r[2] = lo.z; r[3] = lo.w;
  r[4] = hi.x; r[5] = hi.y; r[6] = hi.z; r[7] = hi.w;
  return r;
}

// async global->LDS, 16B per lane; lds base wave-uniform, HW adds lane*16
__device__ __forceinline__ void async_copy16(const unsigned char* g, unsigned char* lds_base) {
  __builtin_amdgcn_global_load_lds(
      (const __attribute__((address_space(1))) unsigned int*)g,
      (__attribute__((address_space(3))) unsigned int*)lds_base,
      16, 0, 0);
}

// ---------- fp32 -> fp8 convert (two arrays, scale 16) ----------
__global__ __launch_bounds__(256) void cvt2_kernel(const float* __restrict__ s1,
                                                   unsigned int* __restrict__ d1, int n1_4,
                                                   const float* __restrict__ s2,
                                                   unsigned int* __restrict__ d2, int n2_4) {
  int i = blockIdx.x * 256 + threadIdx.x;
  const float* s; unsigned int* d; int idx;
  if (i < n1_4) { s = s1; d = d1; idx = i; }
  else if (i < n1_4 + n2_4) { s = s2; d = d2; idx = i - n1_4; }
  else return;
  float4 v = ((const float4*)s)[idx];
  d[idx] = f2fp8x4(v.x * 16.f, v.y * 16.f, v.z * 16.f, v.w * 16.f);
}

// ---------- LayerNorm: one block per row of 1024, fp8 out (scale 1) ----------
__global__ __launch_bounds__(256) void ln_kernel(const float* __restrict__ x,
                                                 const float* __restrict__ gamma,
                                                 const float* __restrict__ beta,
                                                 unsigned int* __restrict__ h) {
  const int row = blockIdx.x;
  const int t = threadIdx.x;
  const float4 v = ((const float4*)(x + (size_t)row * 1024))[t];
  float s  = v.x + v.y + v.z + v.w;
  float s2 = v.x*v.x + v.y*v.y + v.z*v.z + v.w*v.w;
#pragma unroll
  for (int o = 32; o > 0; o >>= 1) {
    s  += __shfl_down(s,  o, 64);
    s2 += __shfl_down(s2, o, 64);
  }
  __shared__ float rs[4], rs2[4];
  const int wid = t >> 6;
  if ((t & 63) == 0) { rs[wid] = s; rs2[wid] = s2; }
  __syncthreads();
  const float S  = rs[0] + rs[1] + rs[2] + rs[3];
  const float S2 = rs2[0] + rs2[1] + rs2[2] + rs2[3];
  const float mu  = S * (1.f / 1024.f);
  const float inv = rsqrtf(S2 * (1.f / 1024.f) - mu * mu + 1e-5f);
  const float4 g = ((const float4*)gamma)[t];
  const float4 b = ((const float4*)beta)[t];
  h[row * 256 + t] = f2fp8x4((v.x - mu) * inv * g.x + b.x,
                             (v.y - mu) * inv * g.y + b.y,
                             (v.z - mu) * inv * g.z + b.z,
                             (v.w - mu) * inv * g.w + b.w);
}

// ---------- q/k projection (fp8 out, scale 16) ----------
__global__ __launch_bounds__(256) void qk_kernel(const unsigned short* __restrict__ uv,
                                                 const float* __restrict__ qkw,
                                                 const float* __restrict__ qkb,
                                                 unsigned char* __restrict__ q,
                                                 unsigned char* __restrict__ k,
                                                 int NU, int baseoff, int S, int total) {
  int i = blockIdx.x * 256 + threadIdx.x;
  if (i < total) {
    int n = i / S, s = i - n * S;
    float base = bf2f(uv[(size_t)n * NU + baseoff + s]);
    q[i] = f2fp8(16.f * (base * qkw[s]     + qkb[s]));
    k[i] = f2fp8(16.f * (base * qkw[S + s] + qkb[S + s]));
  }
}

// ---------- transpose v: vT[e][m] = uv[m][E + e], fp8 out (scale 1) ----------
__global__ __launch_bounds__(256) void transpose_v(const unsigned short* __restrict__ uv,
                                                   unsigned char* __restrict__ vT,
                                                   int n, int NU, int E) {
  __shared__ unsigned short tile[64][68];
  const int tm = blockIdx.x * 64;
  const int te = blockIdx.y * 64;
  const int t = threadIdx.x;
  const int r  = t >> 4;
  const int c4 = (t & 15) * 4;
#pragma unroll
  for (int i = 0; i < 4; ++i) {
    int row = i * 16 + r;
    ushort4 v = *(const ushort4*)(uv + (size_t)(tm + row) * NU + E + te + c4);
    tile[row][c4 + 0] = v.x; tile[row][c4 + 1] = v.y;
    tile[row][c4 + 2] = v.z; tile[row][c4 + 3] = v.w;
  }
  __syncthreads();
#pragma unroll
  for (int i = 0; i < 4; ++i) {
    int erow = i * 16 + r;
    *(unsigned int*)(vT + (size_t)(te + erow) * n + tm + c4) =
        f2fp8x4(bf2f(tile[c4 + 0][erow]), bf2f(tile[c4 + 1][erow]),
                bf2f(tile[c4 + 2][erow]), bf2f(tile[c4 + 3][erow]));
  }
}

// ---------- fp8 MX GEMM: 128x128 tile, BK=128 bytes, NBUF=2, 2 blocks/CU ----------
// R17 = exact revert to R12 (proven 125.6us total / 43.3us GEMM3).
// R16's fused GEMM1 epilogue (triple-branch + 5 extra live pointers on the
// shared template) pushed the EPI=0 instantiation over a regalloc cliff:
// ~1GB/dispatch scratch round-trip, 310us (rule #19/#20). R15's XCD chunking
// broke natural cross-XCD panel sharing (FETCH 49->78MB). Both reverted.
// Mechanism (R12, proven): 64KB LDS -> 2 blocks/CU; one block's MFMA hides
// the other's stage/drain (m114); lookahead-1 STAGE(t+1) before compute(t)
// covers stage latency within a block.
// Schedule per K-tile: { STAGE(t+1 -> wb) ; READ+MFMA(rb) ; vmcnt(0) ;
// barrier }. Races: reads(rb=t&1) need stage(t) retired — prior iter ended
// vmcnt(0)+barrier; stage(t+1) writes wb=(t+1)&1, read last at t-1, its
// ds_reads all consumed by MFMAs (compiler lgkm) before that iter's barrier.
// LDS: 16B-slot XOR swizzle (source slot16^(row&7), read (2kg)^r7/(2kg+1)^r7;
// rule #21 both-sides; numerically proven R6+; 8 lanes/slot = b128 optimum).
// MFMA: v_mfma_scale_f32_16x16x128_f8f6f4, fp8/fp8, unit scales.
// 8 waves = 2Mx4N, wave tile 64x32, acc[4][2]. VGPR 52 + 32 AGPR (no spill).
// EPI 0: silu(acc/16 + bias[col])      -> bf16 D   (A=h, B=16*uvw)
// EPI 1: 8*max(acc,0)^2               -> fp8 D    (= 2^26 * kernel_true)
// EPI 2: u * acc * 2^-2               -> fp8 D    (= 2^24 * ug_true)
// EPI 3: acc*2^-28 + bias[col] + X    -> f32 D
template <int EPI, int KTOT>
__global__ __launch_bounds__(512, 4)
void gemm_f8(const unsigned char* __restrict__ A, int lda,
             const unsigned char* __restrict__ B, int ldb,
             void* __restrict__ D, int ldd,
             const float* __restrict__ bias,
             const unsigned short* __restrict__ U, int ldu,
             const float* __restrict__ X, int ldx) {
  constexpr int NT   = KTOT / 128;
  constexpr int NBUF = (NT == 1) ? 1 : 2;
  constexpr int NN   = 2;
  constexpr int WN   = 32;

  __shared__ __align__(64) unsigned char As[NBUF][128 * 128];   // 16KB per buf
  __shared__ __align__(64) unsigned char Bs[NBUF][128 * 128];   // 16KB per buf

  const int tid  = threadIdx.x;
  const int wid  = tid >> 6;
  const int lane = tid & 63;
  const int bm = blockIdx.x * 128;
  const int bn = blockIdx.y * 128;
  const int wr = wid >> 2;          // 0..1 -> rows wr*64
  const int wc = wid & 3;           // 0..3 -> cols wc*32
  const int frow = lane & 15;
  const int r7   = frow & 7;
  const int kg   = lane >> 4;
  const int s0   = ((2 * kg)     ^ r7) * 16;   // byte slot of K-window lo 16B
  const int s1   = ((2 * kg + 1) ^ r7) * 16;   // byte slot of K-window hi 16B

  // staging: per gload instr, 512 threads cover 64 rows x 128B (wave = 8 rows);
  // LDS[row][slot16] = G[row][slot16 ^ (row&7)] via pre-swizzled source
  const int srow  = tid >> 3;
  const int sslot = (tid & 7) ^ (srow & 7);
  const unsigned char* pA = A + (size_t)(bm + srow) * lda + sslot * 16;
  const unsigned char* pB = B + (size_t)(bn + srow) * ldb + sslot * 16;

#define STAGE(bufidx, k0)                                                                     \
  {                                                                                           \
    _Pragma("unroll")                                                                         \
    for (int i = 0; i < 2; ++i)                                                               \
      async_copy16(pA + (size_t)(i * 64) * lda + (k0), &As[bufidx][(i * 64 + wid * 8) * 128]);\
    _Pragma("unroll")                                                                         \
    for (int j = 0; j < 2; ++j)                                                               \
      async_copy16(pB + (size_t)(j * 64) * ldb + (k0), &Bs[bufidx][(j * 64 + wid * 8) * 128]);\
  }

#define READ_FRAGS(rbuf)                                                                      \
  {                                                                                           \
    _Pragma("unroll")                                                                         \
    for (int m = 0; m < 4; ++m) {                                                             \
      const int base = (wr * 64 + m * 16 + frow) * 128;                                       \
      la[m] = *(const int4*)&As[rbuf][base + s0];                                             \
      ha[m] = *(const int4*)&As[rbuf][base + s1];                                             \
    }                                                                                         \
    _Pragma("unroll")                                                                         \
    for (int n = 0; n < NN; ++n) {                                                            \
      const int base = (wc * WN + n * 16 + frow) * 128;                                       \
      lb[n] = *(const int4*)&Bs[rbuf][base + s0];                                             \
      hb[n] = *(const int4*)&Bs[rbuf][base + s1];                                             \
    }                                                                                         \
  }

#define MFMA_ALL()                                                                            \
  {                                                                                           \
    _Pragma("unroll")                                                                         \
    for (int m = 0; m < 4; ++m) {                                                             \
      const v8i am = mkv8(la[m], ha[m]);                                                      \
      _Pragma("unroll")                                                                       \
      for (int n = 0; n < NN; ++n)                                                            \
        acc[m][n] = __builtin_amdgcn_mfma_scale_f32_16x16x128_f8f6f4(                         \
            am, mkv8(lb[n], hb[n]), acc[m][n], 0, 0, 0, 0x7f7f7f7f, 0, 0x7f7f7f7f);           \
    }                                                                                         \
  }

  f32x4 acc[4][NN] = {};
  int4 la[4], ha[4], lb[NN], hb[NN];

  if constexpr (NT == 1) {
    STAGE(0, 0);
    asm volatile("s_waitcnt vmcnt(0)" ::: "memory");
    __builtin_amdgcn_s_barrier();
    READ_FRAGS(0);
    MFMA_ALL();
  } else {
    STAGE(0, 0);
    asm volatile("s_waitcnt vmcnt(0)" ::: "memory");
    __builtin_amdgcn_s_barrier();
    __builtin_amdgcn_sched_barrier(0);
    for (int t = 0; t < NT; ++t) {
      if (t + 1 < NT) STAGE((t + 1) & 1, ((size_t)(t + 1)) << 7);
      READ_FRAGS(t & 1);
      __builtin_amdgcn_s_setprio(1);
      MFMA_ALL();
      __builtin_amdgcn_s_setprio(0);
      __builtin_amdgcn_sched_barrier(0);
      asm volatile("s_waitcnt vmcnt(0)" ::: "memory");
      __builtin_amdgcn_s_barrier();
      __builtin_amdgcn_sched_barrier(0);
    }
  }

#undef STAGE
#undef READ_FRAGS
#undef MFMA_ALL

  // epilogue (C/D layout: col=lane&15, row=(lane>>4)*4+r — shape-determined)
  const int rbase = (lane >> 4) * 4;
  const int cloc  = lane & 15;
#pragma unroll
  for (int m = 0; m < 4; ++m) {
#pragma unroll
    for (int n = 0; n < NN; ++n) {
      const int col = bn + wc * WN + n * 16 + cloc;
#pragma unroll
      for (int r = 0; r < 4; ++r) {
        const int row = bm + wr * 64 + m * 16 + rbase + r;
        float v = acc[m][n][r];
        if constexpr (EPI == 0) {
          v = v * (1.f / 16.f) + bias[col];
          float sv = v / (1.f + __expf(-v));
          ((unsigned short*)D)[(size_t)row * ldd + col] = f2bf(sv);
        } else if constexpr (EPI == 1) {
          float z = fmaxf(v, 0.f);
          ((unsigned char*)D)[(size_t)row * ldd + col] = f2fp8(8.f * z * z);
        } else if constexpr (EPI == 2) {
          float u = bf2f(U[(size_t)row * ldu + col]);
          ((unsigned char*)D)[(size_t)row * ldd + col] = f2fp8(u * v * 0.25f);
        } else {
          ((float*)D)[(size_t)row * ldd + col] =
              v * (1.f / 268435456.f) + bias[col] + X[(size_t)row * ldx + col];
        }
      }
    }
  }
}

// ---------- launch ----------
extern "C" void kernel_launch(void* const* d_in, const int* in_sizes, int n_in,
                              void* d_out, int out_size, void* d_ws, size_t ws_size,
                              hipStream_t stream) {
  const float* x    = (const float*)d_in[0];
  const float* ln_g = (const float*)d_in[1];
  const float* ln_b = (const float*)d_in[2];
  const float* uv_w = (const float*)d_in[3];
  const float* uv_b = (const float*)d_in[4];
  const float* qk_w = (const float*)d_in[5];
  const float* qk_b = (const float*)d_in[6];
  const float* o_w  = (const float*)d_in[7];
  const float* o_b  = (const float*)d_in[8];
  float* out = (float*)d_out;

  const int H = 1024, E = 2048, S = 128;
  const int NU = 2 * E + S;          // 4224
  const int n = in_sizes[0] / H;     // 4096

  char* p = (char*)d_ws;
  unsigned char* h_f8   = (unsigned char*)p; p += (size_t)n * H;
  unsigned char* uvw_f8 = (unsigned char*)p; p += (size_t)NU * H;
  unsigned char* ow_f8  = (unsigned char*)p; p += (size_t)H * E;
  unsigned short* uv_bf = (unsigned short*)p; p += (size_t)n * NU * 2;
  unsigned char* q_f8   = (unsigned char*)p; p += (size_t)n * S;
  unsigned char* k_f8   = (unsigned char*)p; p += (size_t)n * S;
  unsigned char* vT_f8  = (unsigned char*)p; p += (size_t)E * n;
  unsigned char* ker_f8 = (unsigned char*)p; p += (size_t)n * n;
  unsigned char* ug_f8  = (unsigned char*)p; p += (size_t)n * E;

  const int n1_4 = NU * H / 4, n2_4 = H * E / 4;
  cvt2_kernel<<<(n1_4 + n2_4 + 255) / 256, 256, 0, stream>>>(
      uv_w, (unsigned int*)uvw_f8, n1_4, o_w, (unsigned int*)ow_f8, n2_4);

  ln_kernel<<<n, 256, 0, stream>>>(x, ln_g, ln_b, (unsigned int*)h_f8);

  // uv = silu(h @ uv_w^T + uv_b)   M=4096 N=4224 K=1024 (NT=8) ; 1056 blocks
  gemm_f8<0, 1024><<<dim3(n / 128, NU / 128), 512, 0, stream>>>(
      h_f8, H, uvw_f8, H, uv_bf, NU, uv_b, nullptr, 0, nullptr, 0);

  int tq = n * S;
  qk_kernel<<<(tq + 255) / 256, 256, 0, stream>>>(uv_bf, qk_w, qk_b, q_f8, k_f8, NU, 2 * E, S, tq);

  transpose_v<<<dim3(n / 64, E / 64), 256, 0, stream>>>(uv_bf, vT_f8, n, NU, E);

  // ker_f8 = 2^26 * relu(qk/sqrt(128))^2   M=N=4096 K=128 (NT=1) ; 1024 blocks, 4/CU
  gemm_f8<1, 128><<<dim3(n / 128, n / 128), 512, 0, stream>>>(
      q_f8, S, k_f8, S, ker_f8, n, nullptr, nullptr, 0, nullptr, 0);

  // ug_f8 = 2^24 * u * (kernel @ v)   M=4096 N=2048 K=4096 (NT=32) ; 512 blocks, 2/CU
  gemm_f8<2, 4096><<<dim3(n / 128, E / 128), 512, 0, stream>>>(
      ker_f8, n, vT_f8, n, ug_f8, E, nullptr, uv_bf, NU, nullptr, 0);

  // out = ug @ o_w^T + o_b + x   M=4096 N=1024 K=2048 (NT=16) ; 256 blocks
  gemm_f8<3, 2048><<<dim3(n / 128, H / 128), 512, 0, stream>>>(
      ug_f8, E, ow_f8, E, out, H, o_b, nullptr, 0, x, H);
}

// Round 18
// 122.583 us; speedup vs baseline: 3.0979x; 1.0249x over previous
//
#include <hip/hip_runtime.h>
#include <hip/hip_bf16.h>
#include <stdint.h>

// ---------- helpers ----------
typedef __attribute__((ext_vector_type(8))) int v8i;
typedef __attribute__((ext_vector_type(4))) float f32x4;

__device__ __forceinline__ unsigned short f2bf(float f) {
  union { float f; unsigned int u; } v; v.f = f;
  unsigned int r = (v.u + 0x7fffu + ((v.u >> 16) & 1u)) >> 16;
  return (unsigned short)r;
}
__device__ __forceinline__ float bf2f(unsigned short h) {
  union { float f; unsigned int u; } v; v.u = ((unsigned int)h) << 16; return v.f;
}
// fp8 e4m3 (OCP) converts via HW packer
__device__ __forceinline__ unsigned char f2fp8(float f) {
  int r = __builtin_amdgcn_cvt_pk_fp8_f32(f, 0.f, 0, false);
  return (unsigned char)(r & 0xff);
}
__device__ __forceinline__ unsigned int f2fp8x4(float a, float b, float c, float d) {
  int r = __builtin_amdgcn_cvt_pk_fp8_f32(a, b, 0, false);
  r = __builtin_amdgcn_cvt_pk_fp8_f32(c, d, r, true);
  return (unsigned int)r;
}
// build v8i MFMA operand from two int4 register quads (static indices -> regs)
__device__ __forceinline__ v8i mkv8(int4 lo, int4 hi) {
  v8i r;
  r[0] = lo.x; r[1] = lo.y; r[2] = lo.z; r[3] = lo.w;
  r[4] = hi.x; r[5] = hi.y; r[6] = hi.z; r[7] = hi.w;
  return r;
}

// async global->LDS, 16B per lane; lds base wave-uniform, HW adds lane*16
__device__ __forceinline__ void async_copy16(const unsigned char* g, unsigned char* lds_base) {
  __builtin_amdgcn_global_load_lds(
      (const __attribute__((address_space(1))) unsigned int*)g,
      (__attribute__((address_space(3))) unsigned int*)lds_base,
      16, 0, 0);
}

// ---------- prep: fp32->fp8 converts (scale 16) + LayerNorm, one launch ----------
// blocks [0, cvtB): cvt of uv_w then o_w (flat). blocks [cvtB, cvtB+nrows): LN row.
__global__ __launch_bounds__(256) void prep_kernel(const float* __restrict__ uvw,
                                                   unsigned int* __restrict__ uvw8, int n1_4,
                                                   const float* __restrict__ ow,
                                                   unsigned int* __restrict__ ow8, int n2_4,
                                                   int cvtB,
                                                   const float* __restrict__ x,
                                                   const float* __restrict__ gamma,
                                                   const float* __restrict__ beta,
                                                   unsigned int* __restrict__ h) {
  __shared__ float rs[4], rs2[4];
  const int t = threadIdx.x;
  if ((int)blockIdx.x < cvtB) {
    int i = blockIdx.x * 256 + t;
    const float* s; unsigned int* d; int idx;
    if (i < n1_4) { s = uvw; d = uvw8; idx = i; }
    else if (i < n1_4 + n2_4) { s = ow; d = ow8; idx = i - n1_4; }
    else return;
    float4 v = ((const float4*)s)[idx];
    d[idx] = f2fp8x4(v.x * 16.f, v.y * 16.f, v.z * 16.f, v.w * 16.f);
    return;
  }
  const int row = blockIdx.x - cvtB;
  const float4 v = ((const float4*)(x + (size_t)row * 1024))[t];
  float s  = v.x + v.y + v.z + v.w;
  float s2 = v.x*v.x + v.y*v.y + v.z*v.z + v.w*v.w;
#pragma unroll
  for (int o = 32; o > 0; o >>= 1) {
    s  += __shfl_down(s,  o, 64);
    s2 += __shfl_down(s2, o, 64);
  }
  const int wid = t >> 6;
  if ((t & 63) == 0) { rs[wid] = s; rs2[wid] = s2; }
  __syncthreads();
  const float S  = rs[0] + rs[1] + rs[2] + rs[3];
  const float S2 = rs2[0] + rs2[1] + rs2[2] + rs2[3];
  const float mu  = S * (1.f / 1024.f);
  const float inv = rsqrtf(S2 * (1.f / 1024.f) - mu * mu + 1e-5f);
  const float4 g = ((const float4*)gamma)[t];
  const float4 b = ((const float4*)beta)[t];
  h[row * 256 + t] = f2fp8x4((v.x - mu) * inv * g.x + b.x,
                             (v.y - mu) * inv * g.y + b.y,
                             (v.z - mu) * inv * g.z + b.z,
                             (v.w - mu) * inv * g.w + b.w);
}

// ---------- post: v-transpose + q/k projection, one launch ----------
// blocks [0, 2048): transpose tile (bx=id&63 -> m, by=id>>6 -> e).
// blocks [2048, 4096): qk elementwise.
__global__ __launch_bounds__(256) void post_kernel(const unsigned short* __restrict__ uv,
                                                   unsigned char* __restrict__ vT,
                                                   const float* __restrict__ qkw,
                                                   const float* __restrict__ qkb,
                                                   unsigned char* __restrict__ q,
                                                   unsigned char* __restrict__ k,
                                                   int n, int NU, int E, int S) {
  __shared__ unsigned short tile[64][68];
  const int t = threadIdx.x;
  if ((int)blockIdx.x >= 2048) {
    int i = ((int)blockIdx.x - 2048) * 256 + t;
    int nn = i / S, s = i - nn * S;
    float base = bf2f(uv[(size_t)nn * NU + 2 * E + s]);
    q[i] = f2fp8(16.f * (base * qkw[s]     + qkb[s]));
    k[i] = f2fp8(16.f * (base * qkw[S + s] + qkb[S + s]));
    return;
  }
  const int tm = ((int)blockIdx.x & 63) * 64;
  const int te = ((int)blockIdx.x >> 6) * 64;
  const int r  = t >> 4;
  const int c4 = (t & 15) * 4;
#pragma unroll
  for (int i = 0; i < 4; ++i) {
    int row = i * 16 + r;
    ushort4 v = *(const ushort4*)(uv + (size_t)(tm + row) * NU + E + te + c4);
    tile[row][c4 + 0] = v.x; tile[row][c4 + 1] = v.y;
    tile[row][c4 + 2] = v.z; tile[row][c4 + 3] = v.w;
  }
  __syncthreads();
#pragma unroll
  for (int i = 0; i < 4; ++i) {
    int erow = i * 16 + r;
    *(unsigned int*)(vT + (size_t)(te + erow) * n + tm + c4) =
        f2fp8x4(bf2f(tile[c4 + 0][erow]), bf2f(tile[c4 + 1][erow]),
                bf2f(tile[c4 + 2][erow]), bf2f(tile[c4 + 3][erow]));
  }
}

// ---------- fp8 MX GEMM: 128xBN tile, BK=128 bytes, NBUF=2 ----------
// R18 = R12 structure (proven 43.3us GEMM3) + BN template param.
// BN=128 (EPI 0/1/2): byte-identical geometry to R12 — 8 waves 2Mx4N,
//   wave tile 64x32, acc[4][2], 64KB LDS -> 2 blocks/CU.
// BN=64 (EPI 3 / GEMM4): fixes GEMM4's missing co-residency (grid was
//   256 blocks = 1/CU -> serial phases). Now grid 32x16=512, LDS 48KB ->
//   3 blocks/CU, 8 waves 4Mx2N of 32x32 tiles, acc[2][2] (tiny reg use).
// Schedule per K-tile: { STAGE(t+1 -> wb) ; READ+MFMA(rb) ; vmcnt(0) ;
// barrier }. Races: reads(rb=t&1) need stage(t) retired — prior iter ended
// vmcnt(0)+barrier; stage(t+1) writes wb=(t+1)&1, read last at t-1, its
// ds_reads all consumed by MFMAs (compiler lgkm) before that iter's barrier.
// LDS: 16B-slot XOR swizzle (source slot16^(row&7), read (2kg)^r7/(2kg+1)^r7;
// rule #21 both-sides; numerically proven R6+).
// MFMA: v_mfma_scale_f32_16x16x128_f8f6f4, fp8/fp8, unit scales.
// EPI 0: silu(acc/16 + bias[col])      -> bf16 D   (A=h, B=16*uvw)
// EPI 1: 8*max(acc,0)^2               -> fp8 D    (= 2^26 * kernel_true)
// EPI 2: u * acc * 2^-2               -> fp8 D    (= 2^24 * ug_true)
// EPI 3: acc*2^-28 + bias[col] + X    -> f32 D
template <int EPI, int KTOT, int BN>
__global__ __launch_bounds__(512, 4)
void gemm_f8(const unsigned char* __restrict__ A, int lda,
             const unsigned char* __restrict__ B, int ldb,
             void* __restrict__ D, int ldd,
             const float* __restrict__ bias,
             const unsigned short* __restrict__ U, int ldu,
             const float* __restrict__ X, int ldx) {
  constexpr int NT   = KTOT / 128;
  constexpr int NBUF = (NT == 1) ? 1 : 2;
  constexpr int MM   = (BN == 128) ? 4 : 2;   // A m-repeats (wave rows = MM*16)
  constexpr int NN   = 2;
  constexpr int WM   = MM * 16;               // wave row span
  constexpr int BIT  = BN / 64;               // B gloads per tile

  __shared__ __align__(64) unsigned char As[NBUF][128 * 128];
  __shared__ __align__(64) unsigned char Bs[NBUF][BN * 128];

  const int tid  = threadIdx.x;
  const int wid  = tid >> 6;
  const int lane = tid & 63;
  const int bm = blockIdx.x * 128;
  const int bn = blockIdx.y * BN;
  const int wr = (BN == 128) ? (wid >> 2) : (wid >> 1);
  const int wc = (BN == 128) ? (wid & 3)  : (wid & 1);
  const int frow = lane & 15;
  const int r7   = frow & 7;
  const int kg   = lane >> 4;
  const int s0   = ((2 * kg)     ^ r7) * 16;   // byte slot of K-window lo 16B
  const int s1   = ((2 * kg + 1) ^ r7) * 16;   // byte slot of K-window hi 16B

  // staging: per gload instr, 512 threads cover 64 rows x 128B (wave = 8 rows);
  // LDS[row][slot16] = G[row][slot16 ^ (row&7)] via pre-swizzled source
  const int srow  = tid >> 3;
  const int sslot = (tid & 7) ^ (srow & 7);
  const unsigned char* pA = A + (size_t)(bm + srow) * lda + sslot * 16;
  const unsigned char* pB = B + (size_t)(bn + srow) * ldb + sslot * 16;

#define STAGE(bufidx, k0)                                                                     \
  {                                                                                           \
    _Pragma("unroll")                                                                         \
    for (int i = 0; i < 2; ++i)                                                               \
      async_copy16(pA + (size_t)(i * 64) * lda + (k0), &As[bufidx][(i * 64 + wid * 8) * 128]);\
    _Pragma("unroll")                                                                         \
    for (int j = 0; j < BIT; ++j)                                                             \
      async_copy16(pB + (size_t)(j * 64) * ldb + (k0), &Bs[bufidx][(j * 64 + wid * 8) * 128]);\
  }

#define READ_FRAGS(rbuf)                                                                      \
  {                                                                                           \
    _Pragma("unroll")                                                                         \
    for (int m = 0; m < MM; ++m) {                                                            \
      const int base = (wr * WM + m * 16 + frow) * 128;                                       \
      la[m] = *(const int4*)&As[rbuf][base + s0];                                             \
      ha[m] = *(const int4*)&As[rbuf][base + s1];                                             \
    }                                                                                         \
    _Pragma("unroll")                                                                         \
    for (int n = 0; n < NN; ++n) {                                                            \
      const int base = (wc * 32 + n * 16 + frow) * 128;                                       \
      lb[n] = *(const int4*)&Bs[rbuf][base + s0];                                             \
      hb[n] = *(const int4*)&Bs[rbuf][base + s1];                                             \
    }                                                                                         \
  }

#define MFMA_ALL()                                                                            \
  {                                                                                           \
    _Pragma("unroll")                                                                         \
    for (int m = 0; m < MM; ++m) {                                                            \
      const v8i am = mkv8(la[m], ha[m]);                                                      \
      _Pragma("unroll")                                                                       \
      for (int n = 0; n < NN; ++n)                                                            \
        acc[m][n] = __builtin_amdgcn_mfma_scale_f32_16x16x128_f8f6f4(                         \
            am, mkv8(lb[n], hb[n]), acc[m][n], 0, 0, 0, 0x7f7f7f7f, 0, 0x7f7f7f7f);           \
    }                                                                                         \
  }

  f32x4 acc[MM][NN] = {};
  int4 la[MM], ha[MM], lb[NN], hb[NN];

  if constexpr (NT == 1) {
    STAGE(0, 0);
    asm volatile("s_waitcnt vmcnt(0)" ::: "memory");
    __builtin_amdgcn_s_barrier();
    READ_FRAGS(0);
    MFMA_ALL();
  } else {
    STAGE(0, 0);
    asm volatile("s_waitcnt vmcnt(0)" ::: "memory");
    __builtin_amdgcn_s_barrier();
    __builtin_amdgcn_sched_barrier(0);
    for (int t = 0; t < NT; ++t) {
      if (t + 1 < NT) STAGE((t + 1) & 1, ((size_t)(t + 1)) << 7);
      READ_FRAGS(t & 1);
      __builtin_amdgcn_s_setprio(1);
      MFMA_ALL();
      __builtin_amdgcn_s_setprio(0);
      __builtin_amdgcn_sched_barrier(0);
      asm volatile("s_waitcnt vmcnt(0)" ::: "memory");
      __builtin_amdgcn_s_barrier();
      __builtin_amdgcn_sched_barrier(0);
    }
  }

#undef STAGE
#undef READ_FRAGS
#undef MFMA_ALL

  // epilogue (C/D layout: col=lane&15, row=(lane>>4)*4+r — shape-determined)
  const int rbase = (lane >> 4) * 4;
  const int cloc  = lane & 15;
#pragma unroll
  for (int m = 0; m < MM; ++m) {
#pragma unroll
    for (int n = 0; n < NN; ++n) {
      const int col = bn + wc * 32 + n * 16 + cloc;
#pragma unroll
      for (int r = 0; r < 4; ++r) {
        const int row = bm + wr * WM + m * 16 + rbase + r;
        float v = acc[m][n][r];
        if constexpr (EPI == 0) {
          v = v * (1.f / 16.f) + bias[col];
          float sv = v / (1.f + __expf(-v));
          ((unsigned short*)D)[(size_t)row * ldd + col] = f2bf(sv);
        } else if constexpr (EPI == 1) {
          float z = fmaxf(v, 0.f);
          ((unsigned char*)D)[(size_t)row * ldd + col] = f2fp8(8.f * z * z);
        } else if constexpr (EPI == 2) {
          float u = bf2f(U[(size_t)row * ldu + col]);
          ((unsigned char*)D)[(size_t)row * ldd + col] = f2fp8(u * v * 0.25f);
        } else {
          ((float*)D)[(size_t)row * ldd + col] =
              v * (1.f / 268435456.f) + bias[col] + X[(size_t)row * ldx + col];
        }
      }
    }
  }
}

// ---------- launch ----------
extern "C" void kernel_launch(void* const* d_in, const int* in_sizes, int n_in,
                              void* d_out, int out_size, void* d_ws, size_t ws_size,
                              hipStream_t stream) {
  const float* x    = (const float*)d_in[0];
  const float* ln_g = (const float*)d_in[1];
  const float* ln_b = (const float*)d_in[2];
  const float* uv_w = (const float*)d_in[3];
  const float* uv_b = (const float*)d_in[4];
  const float* qk_w = (const float*)d_in[5];
  const float* qk_b = (const float*)d_in[6];
  const float* o_w  = (const float*)d_in[7];
  const float* o_b  = (const float*)d_in[8];
  float* out = (float*)d_out;

  const int H = 1024, E = 2048, S = 128;
  const int NU = 2 * E + S;          // 4224
  const int n = in_sizes[0] / H;     // 4096

  char* p = (char*)d_ws;
  unsigned char* h_f8   = (unsigned char*)p; p += (size_t)n * H;
  unsigned char* uvw_f8 = (unsigned char*)p; p += (size_t)NU * H;
  unsigned char* ow_f8  = (unsigned char*)p; p += (size_t)H * E;
  unsigned short* uv_bf = (unsigned short*)p; p += (size_t)n * NU * 2;
  unsigned char* q_f8   = (unsigned char*)p; p += (size_t)n * S;
  unsigned char* k_f8   = (unsigned char*)p; p += (size_t)n * S;
  unsigned char* vT_f8  = (unsigned char*)p; p += (size_t)E * n;
  unsigned char* ker_f8 = (unsigned char*)p; p += (size_t)n * n;
  unsigned char* ug_f8  = (unsigned char*)p; p += (size_t)n * E;

  const int n1_4 = NU * H / 4, n2_4 = H * E / 4;
  const int cvtB = (n1_4 + n2_4 + 255) / 256;

  // cvt(uv_w, o_w) + LayerNorm in one launch
  prep_kernel<<<cvtB + n, 256, 0, stream>>>(
      uv_w, (unsigned int*)uvw_f8, n1_4, o_w, (unsigned int*)ow_f8, n2_4, cvtB,
      x, ln_g, ln_b, (unsigned int*)h_f8);

  // uv = silu(h @ uv_w^T + uv_b)   M=4096 N=4224 K=1024 (NT=8) ; 1056 blocks
  gemm_f8<0, 1024, 128><<<dim3(n / 128, NU / 128), 512, 0, stream>>>(
      h_f8, H, uvw_f8, H, uv_bf, NU, uv_b, nullptr, 0, nullptr, 0);

  // v-transpose + q/k projection in one launch (4096 blocks)
  post_kernel<<<4096, 256, 0, stream>>>(
      uv_bf, vT_f8, qk_w, qk_b, q_f8, k_f8, n, NU, E, S);

  // ker_f8 = 2^26 * relu(qk/sqrt(128))^2   M=N=4096 K=128 (NT=1) ; 1024 blocks
  gemm_f8<1, 128, 128><<<dim3(n / 128, n / 128), 512, 0, stream>>>(
      q_f8, S, k_f8, S, ker_f8, n, nullptr, nullptr, 0, nullptr, 0);

  // ug_f8 = 2^24 * u * (kernel @ v)   M=4096 N=2048 K=4096 (NT=32) ; 512 blocks, 2/CU
  gemm_f8<2, 4096, 128><<<dim3(n / 128, E / 128), 512, 0, stream>>>(
      ker_f8, n, vT_f8, n, ug_f8, E, nullptr, uv_bf, NU, nullptr, 0);

  // out = ug @ o_w^T + o_b + x   M=4096 N=1024 K=2048 (NT=16) ; BN=64 -> 512 blocks, 3/CU
  gemm_f8<3, 2048, 64><<<dim3(n / 128, H / 64), 512, 0, stream>>>(
      ug_f8, E, ow_f8, E, out, H, o_b, nullptr, 0, x, H);
}